// Round 11
// baseline (284.278 us; speedup 1.0000x reference)
//
#include <hip/hip_runtime.h>
#include <hip/hip_bf16.h>
#include <math.h>

#define N_NODES 100000
#define N_EDGES 1600000
#define IN_F 256
#define HID 32
#define OUTC 16
#define NBUCK 1000
#define BUCK_W 100     // NBUCK * BUCK_W == N_NODES
#define NBB 256        // partition blocks
#define CHUNK 6250     // N_EDGES / NBB
#define MAXE 4096      // per-chunk edge capacity in LDS

typedef unsigned short ushort_t;
typedef unsigned int uint_t;

__device__ inline ushort_t f2bf(float f) {
    union { float f; uint_t u; } v; v.f = f;
    uint_t r = v.u + 0x7fff + ((v.u >> 16) & 1);   // round-to-nearest-even
    return (ushort_t)(r >> 16);
}
__device__ inline float bf2f(ushort_t h) {
    union { uint_t u; float f; } v; v.u = (uint_t)h << 16;
    return v.f;
}

// ============ Pass 1: per-block bucket histogram (LDS only) ============
__global__ __launch_bounds__(256) void k_cnt(const int* __restrict__ ei, int* __restrict__ bhist)
{
    __shared__ int lh[NBUCK];
    const int t = threadIdx.x;
    const int blk = blockIdx.x;
    for (int b = t; b < NBUCK; b += 256) lh[b] = 0;
    __syncthreads();
    const int base = blk * CHUNK;
    for (int i = t; i < CHUNK; i += 256) {
        const int dst = ei[N_EDGES + base + i];
        atomicAdd(&lh[dst / BUCK_W], 1);
    }
    __syncthreads();
    for (int b = t; b < NBUCK; b += 256) bhist[b * NBB + blk] = lh[b];
}

// ============ Pass 2a: scan each bucket's 256 block-counts ============
__global__ __launch_bounds__(256) void k_scanH(const int* __restrict__ bhist,
                                               int* __restrict__ boffB, int* __restrict__ btot)
{
    __shared__ int sh[256];
    const int t = threadIdx.x;
    const int b = blockIdx.x;
    const int v = bhist[b * NBB + t];
    sh[t] = v;
    __syncthreads();
    #pragma unroll
    for (int off = 1; off < 256; off <<= 1) {
        const int u = (t >= off) ? sh[t - off] : 0;
        __syncthreads();
        sh[t] += u;
        __syncthreads();
    }
    boffB[b * NBB + t] = sh[t] - v;
    if (t == 255) btot[b] = sh[255];
}

// ============ Pass 2b: scan bucket totals -> bucket start offsets ============
__global__ __launch_bounds__(1024) void k_scanH2(const int* __restrict__ btot,
                                                 int* __restrict__ bstart)
{
    __shared__ int sh[1024];
    const int t = threadIdx.x;
    const int v = (t < NBUCK) ? btot[t] : 0;
    sh[t] = v;
    __syncthreads();
    #pragma unroll
    for (int off = 1; off < 1024; off <<= 1) {
        const int u = (t >= off) ? sh[t - off] : 0;
        __syncthreads();
        sh[t] += u;
        __syncthreads();
    }
    if (t < NBUCK) bstart[t] = sh[t] - v;
    if (t == NBUCK - 1) bstart[NBUCK] = sh[t];
}

// ============ Pass 3: scatter edges into bucket-contiguous packed pairs ============
// pairsP[pos] = (dst % BUCK_W) << 17 | src
__global__ __launch_bounds__(256) void k_scat(const int* __restrict__ ei,
                                              const int* __restrict__ boffB,
                                              const int* __restrict__ bstart,
                                              int* __restrict__ pairsP)
{
    __shared__ int lcur[NBUCK];
    const int t = threadIdx.x;
    const int blk = blockIdx.x;
    for (int b = t; b < NBUCK; b += 256) lcur[b] = bstart[b] + boffB[b * NBB + blk];
    __syncthreads();
    const int base = blk * CHUNK;
    for (int i = t; i < CHUNK; i += 256) {
        const int src = ei[base + i];
        const int dst = ei[N_EDGES + base + i];
        const int b = dst / BUCK_W;
        const int pos = atomicAdd(&lcur[b], 1);
        pairsP[pos] = ((dst - b * BUCK_W) << 17) | src;
    }
}

// ============ Weight fusion: W' = W1b @ W1a  [32][256], b' = W1b@b1a + b1b ============
__global__ __launch_bounds__(256) void k_wfuse(
    const float* __restrict__ w1a_w, const float* __restrict__ w1a_b,
    const float* __restrict__ w1b_w, const float* __restrict__ w1b_b,
    float* __restrict__ wp, float* __restrict__ bp)
{
    __shared__ float wb_s[32][32];
    __shared__ float ba_s[32];
    const int t = threadIdx.x;
    for (int i = t; i < 1024; i += 256) wb_s[i >> 5][i & 31] = w1b_w[i];
    if (t < 32) ba_s[t] = w1a_b[t];
    __syncthreads();
    const int k = t;                       // 0..255
    for (int o = 0; o < 32; ++o) {
        float s = 0.f;
        #pragma unroll 8
        for (int c = 0; c < 32; ++c) s += wb_s[o][c] * w1a_w[c * 256 + k];
        wp[o * 256 + k] = s;
    }
    if (t < 32) {
        float s = 0.f;
        for (int c = 0; c < 32; ++c) s += wb_s[t][c] * ba_s[c];
        bp[t] = s + w1b_b[t];
    }
}

// ============ Layer 1 GEMM: parity 0 -> h1b = bf16(x@W1a^T+b1a); parity 1 -> out1 = x@W'^T+b' ====
// wsT[256][33] transposed weights: conflict-free reads/writes; 33.8KB LDS -> 4 blocks/CU.
__global__ __launch_bounds__(256, 4) void k1_gemm(
    const float* __restrict__ x,
    const float* __restrict__ w1a_w, const float* __restrict__ w1a_b,
    const float* __restrict__ wp, const float* __restrict__ bp,
    ushort_t* __restrict__ h1b, float* __restrict__ out1)
{
    __shared__ float wsT[256][33];

    const int t = threadIdx.x;
    const int parity = blockIdx.x & 1;
    const int node0 = (int)(blockIdx.x >> 1) * 256;
    const float* __restrict__ wsel = parity ? wp : w1a_w;
    const float* __restrict__ bsel = parity ? bp : w1a_b;

    for (int i = t; i < 32 * 256; i += 256) {
        const int o = i >> 8, k = i & 255;
        wsT[k][o] = wsel[i];               // lanes write stride-33 -> 2 lanes/bank (free)
    }
    __syncthreads();

    const int og = t & 3;
    const int ng = t >> 2;
    const int o0 = og * 8;

    int nid[4]; bool val[4];
    #pragma unroll
    for (int j = 0; j < 4; ++j) { nid[j] = node0 + ng * 4 + j; val[j] = nid[j] < N_NODES; }

    float bias[8];
    #pragma unroll
    for (int o = 0; o < 8; ++o) bias[o] = bsel[o0 + o];

    float acc[4][8] = {};
    for (int kc = 0; kc < 64; ++kc) {
        float4 x4[4];
        #pragma unroll
        for (int j = 0; j < 4; ++j) {
            x4[j] = val[j] ? ((const float4*)(x + (size_t)nid[j] * IN_F))[kc]
                           : make_float4(0.f, 0.f, 0.f, 0.f);
        }
        #pragma unroll
        for (int u = 0; u < 4; ++u) {
            const int k = kc * 4 + u;
            const float4 wA = *(const float4*)&wsT[k][o0];     // banks {o0..o0+3}+k*33
            const float4 wB = *(const float4*)&wsT[k][o0 + 4];
            #pragma unroll
            for (int j = 0; j < 4; ++j) {
                const float xv = (u == 0) ? x4[j].x : (u == 1) ? x4[j].y
                               : (u == 2) ? x4[j].z : x4[j].w;
                acc[j][0] += xv * wA.x; acc[j][1] += xv * wA.y;
                acc[j][2] += xv * wA.z; acc[j][3] += xv * wA.w;
                acc[j][4] += xv * wB.x; acc[j][5] += xv * wB.y;
                acc[j][6] += xv * wB.z; acc[j][7] += xv * wB.w;
            }
        }
    }

    #pragma unroll
    for (int j = 0; j < 4; ++j) {
        if (!val[j]) continue;
        float vv[8];
        #pragma unroll
        for (int o = 0; o < 8; ++o) vv[o] = acc[j][o] + bias[o];
        if (parity == 0) {
            uint4 pk;
            pk.x = (uint_t)f2bf(vv[0]) | ((uint_t)f2bf(vv[1]) << 16);
            pk.y = (uint_t)f2bf(vv[2]) | ((uint_t)f2bf(vv[3]) << 16);
            pk.z = (uint_t)f2bf(vv[4]) | ((uint_t)f2bf(vv[5]) << 16);
            pk.w = (uint_t)f2bf(vv[6]) | ((uint_t)f2bf(vv[7]) << 16);
            *(uint4*)(h1b + (size_t)nid[j] * HID + o0) = pk;
        } else {
            float* dst = out1 + (size_t)nid[j] * HID + o0;
            *(float4*)dst       = make_float4(vv[0], vv[1], vv[2], vv[3]);
            *(float4*)(dst + 4) = make_float4(vv[4], vv[5], vv[6], vv[7]);
        }
    }
}

// ============ Aggregate layer 1: in-LDS counting sort, register accumulate ============
__global__ __launch_bounds__(256) void k_agg32(const int* __restrict__ bstart,
                                               const int* __restrict__ pairsP,
                                               const ushort_t* __restrict__ h1b,
                                               float* __restrict__ out1)
{
    __shared__ int cnt[128];
    __shared__ int off[129];
    __shared__ int srt[MAXE];
    const int t = threadIdx.x;
    const int b = blockIdx.x;
    const int c = t & 31;
    const int grp = t >> 5;                 // 8 groups of 32 lanes

    const int e0g = bstart[b];
    const int e1g = bstart[b + 1];

    for (int ch0 = e0g; ch0 < e1g; ch0 += MAXE) {
        const int ce = (ch0 + MAXE < e1g) ? (ch0 + MAXE) : e1g;
        const int cn = ce - ch0;

        if (t < 128) cnt[t] = 0;
        __syncthreads();
        for (int i = t; i < cn; i += 256)
            atomicAdd(&cnt[pairsP[ch0 + i] >> 17], 1);
        __syncthreads();
        {
            int v = (t < 128) ? cnt[t] : 0;
            if (t < 128) off[t] = v;
            __syncthreads();
            #pragma unroll
            for (int o = 1; o < 128; o <<= 1) {
                int u = 0;
                if (t < 128 && t >= o) u = off[t - o];
                __syncthreads();
                if (t < 128) off[t] += u;
                __syncthreads();
            }
            if (t < 128) {
                const int inc = off[t];
                off[t] = inc - v;
                cnt[t] = inc - v;
                if (t == 127) off[128] = inc;
            }
        }
        __syncthreads();
        for (int i = t; i < cn; i += 256) {
            const int p = pairsP[ch0 + i];
            const int pos = atomicAdd(&cnt[p >> 17], 1);
            srt[pos] = p & 0x1FFFF;
        }
        __syncthreads();
        for (int n = grp; n < BUCK_W; n += 8) {
            const int e0 = off[n];
            const int e1 = off[n + 1];
            float acc = 0.f, acc2 = 0.f;
            int e = e0;
            for (; e + 1 < e1; e += 2) {
                const int s0 = srt[e];
                const int s1 = srt[e + 1];
                const float v0 = bf2f(h1b[(size_t)s0 * HID + c]);
                const float v1 = bf2f(h1b[(size_t)s1 * HID + c]);
                acc += v0; acc2 += v1;
            }
            if (e < e1) acc += bf2f(h1b[(size_t)srt[e] * HID + c]);
            acc += acc2;
            out1[((size_t)b * BUCK_W + n) * HID + c] += acc;
        }
        __syncthreads();
    }
}

// ============ Layer 2 dense ============
__global__ __launch_bounds__(256) void k3_layer2_dense(
    const float* __restrict__ out1,
    const float* __restrict__ w2a_w, const float* __restrict__ w2a_b,
    const float* __restrict__ w2b_w, const float* __restrict__ w2b_b,
    ushort_t* __restrict__ h2b, float* __restrict__ out2)
{
    __shared__ float rs[64][33];
    __shared__ float h2s[64][17];
    __shared__ float wa[16][33];
    __shared__ float wb[16][17];

    const int t = threadIdx.x;
    const int node0 = blockIdx.x * 64;
    const int nrem = N_NODES - node0;

    for (int i = t; i < 16 * 32; i += 256)
        wa[i >> 5][i & 31] = w2a_w[i];
    if (t < 16 * 16) wb[t >> 4][t & 15] = w2b_w[t];
    for (int i = t; i < 64 * 32; i += 256) {
        int r = i >> 5, c = i & 31;
        float v = 0.f;
        if (r < nrem) v = out1[(size_t)(node0 + r) * HID + c];
        rs[r][c] = fmaxf(v, 0.f);
    }
    __syncthreads();

    const int o = t & 15;
    const int g = t >> 4;

    const float ba = w2a_b[o];
    float acc[4] = {};
    for (int c = 0; c < 32; ++c) {
        const float w = wa[o][c];
        #pragma unroll
        for (int j = 0; j < 4; ++j) acc[j] += rs[g * 4 + j][c] * w;
    }
    #pragma unroll
    for (int j = 0; j < 4; ++j) {
        const int ln = g * 4 + j;
        const float v = acc[j] + ba;
        h2s[ln][o] = v;
        if (ln < nrem) h2b[(size_t)(node0 + ln) * OUTC + o] = f2bf(v);
    }
    __syncthreads();

    const float bbv = w2b_b[o];
    float f[4] = {};
    for (int c = 0; c < 16; ++c) {
        const float w = wb[o][c];
        #pragma unroll
        for (int j = 0; j < 4; ++j) f[j] += h2s[g * 4 + j][c] * w;
    }
    #pragma unroll
    for (int j = 0; j < 4; ++j) {
        const int ln = g * 4 + j;
        if (ln < nrem) out2[(size_t)(node0 + ln) * OUTC + o] = f[j] + bbv;
    }
}

// ============ Aggregate layer 2 (sorted, register acc) + fused log_softmax ============
__global__ __launch_bounds__(256) void k_agg16_sm(const int* __restrict__ bstart,
                                                  const int* __restrict__ pairsP,
                                                  const ushort_t* __restrict__ h2b,
                                                  float* __restrict__ out2)
{
    __shared__ int cnt[128];
    __shared__ int off[129];
    __shared__ int srt[MAXE];
    const int t = threadIdx.x;
    const int b = blockIdx.x;
    const int c = t & 15;
    const int grp = t >> 4;                 // 16 groups of 16 lanes

    const int e0g = bstart[b];
    const int e1g = bstart[b + 1];

    for (int ch0 = e0g; ch0 < e1g; ch0 += MAXE) {
        const int ce = (ch0 + MAXE < e1g) ? (ch0 + MAXE) : e1g;
        const int cn = ce - ch0;
        const bool last = (ce == e1g);

        if (t < 128) cnt[t] = 0;
        __syncthreads();
        for (int i = t; i < cn; i += 256)
            atomicAdd(&cnt[pairsP[ch0 + i] >> 17], 1);
        __syncthreads();
        {
            int v = (t < 128) ? cnt[t] : 0;
            if (t < 128) off[t] = v;
            __syncthreads();
            #pragma unroll
            for (int o = 1; o < 128; o <<= 1) {
                int u = 0;
                if (t < 128 && t >= o) u = off[t - o];
                __syncthreads();
                if (t < 128) off[t] += u;
                __syncthreads();
            }
            if (t < 128) {
                const int inc = off[t];
                off[t] = inc - v;
                cnt[t] = inc - v;
                if (t == 127) off[128] = inc;
            }
        }
        __syncthreads();
        for (int i = t; i < cn; i += 256) {
            const int p = pairsP[ch0 + i];
            const int pos = atomicAdd(&cnt[p >> 17], 1);
            srt[pos] = p & 0x1FFFF;
        }
        __syncthreads();

        for (int n = grp; n < BUCK_W; n += 16) {
            const int e0 = off[n];
            const int e1 = off[n + 1];
            float acc = 0.f, acc2 = 0.f;
            int e = e0;
            for (; e + 1 < e1; e += 2) {
                const int s0 = srt[e];
                const int s1 = srt[e + 1];
                const float v0 = bf2f(h2b[(size_t)s0 * OUTC + c]);
                const float v1 = bf2f(h2b[(size_t)s1 * OUTC + c]);
                acc += v0; acc2 += v1;
            }
            if (e < e1) acc += bf2f(h2b[(size_t)srt[e] * OUTC + c]);
            acc += acc2;

            const size_t oidx = ((size_t)b * BUCK_W + n) * OUTC + c;
            if (!last) {
                out2[oidx] += acc;
            } else {
                const float val = out2[oidx] + acc;
                float m = val;
                #pragma unroll
                for (int o = 8; o > 0; o >>= 1)
                    m = fmaxf(m, __shfl_xor(m, o, 16));
                float s = expf(val - m);
                #pragma unroll
                for (int o = 8; o > 0; o >>= 1)
                    s += __shfl_xor(s, o, 16);
                const float lse = m + logf(s);
                out2[oidx] = val - lse;
            }
        }
        __syncthreads();
    }
}

extern "C" void kernel_launch(void* const* d_in, const int* in_sizes, int n_in,
                              void* d_out, int out_size, void* d_ws, size_t ws_size,
                              hipStream_t stream)
{
    const float* x      = (const float*)d_in[0];
    const float* w1a_w  = (const float*)d_in[1];
    const float* w1a_b  = (const float*)d_in[2];
    const float* w1b_w  = (const float*)d_in[3];
    const float* w1b_b  = (const float*)d_in[4];
    const float* w2a_w  = (const float*)d_in[5];
    const float* w2a_b  = (const float*)d_in[6];
    const float* w2b_w  = (const float*)d_in[7];
    const float* w2b_b  = (const float*)d_in[8];
    const int*   ei     = (const int*)d_in[9];
    float* out = (float*)d_out;

    // workspace (~31 MB)
    float*    out1   = (float*)d_ws;                              // 12.8 MB
    ushort_t* h1b    = (ushort_t*)(out1 + (size_t)N_NODES * HID); // 6.4 MB
    ushort_t* h2b    = h1b + (size_t)N_NODES * HID;               // 3.2 MB
    int*      pairsP = (int*)(h2b + (size_t)N_NODES * OUTC);      // 6.4 MB
    int*      bhist  = pairsP + N_EDGES;                          // 1 MB
    int*      boffB  = bhist + NBUCK * NBB;                       // 1 MB
    int*      btot   = boffB + NBUCK * NBB;                       // 1000
    int*      bstart = btot + NBUCK;                              // 1001
    float*    wp     = (float*)(bstart + NBUCK + 1);              // 32*256 f32
    float*    bp     = wp + 32 * 256;                             // 32 f32

    k_cnt   <<<NBB, 256, 0, stream>>>(ei, bhist);
    k_scanH <<<NBUCK, 256, 0, stream>>>(bhist, boffB, btot);
    k_scanH2<<<1, 1024, 0, stream>>>(btot, bstart);
    k_scat  <<<NBB, 256, 0, stream>>>(ei, boffB, bstart, pairsP);
    k_wfuse <<<1, 256, 0, stream>>>(w1a_w, w1a_b, w1b_w, w1b_b, wp, bp);

    const int nblk2 = 2 * ((N_NODES + 255) / 256);                // 782
    k1_gemm<<<nblk2, 256, 0, stream>>>(x, w1a_w, w1a_b, wp, bp, h1b, out1);
    k_agg32<<<NBUCK, 256, 0, stream>>>(bstart, pairsP, h1b, out1);
    k3_layer2_dense<<<(N_NODES + 63) / 64, 256, 0, stream>>>(out1, w2a_w, w2a_b, w2b_w, w2b_b, h2b, out);
    k_agg16_sm<<<NBUCK, 256, 0, stream>>>(bstart, pairsP, h2b, out);
}

// Round 12
// 265.997 us; speedup vs baseline: 1.0687x; 1.0687x over previous
//
#include <hip/hip_runtime.h>
#include <hip/hip_bf16.h>
#include <math.h>

#define N_NODES 100000
#define N_EDGES 1600000
#define IN_F 256
#define HID 32
#define OUTC 16
#define NBUCK 1000
#define BUCK_W 100     // NBUCK * BUCK_W == N_NODES
#define NBB 256        // partition blocks
#define CHUNK 6250     // N_EDGES / NBB
#define MAXE 4096      // per-chunk edge capacity in LDS

typedef unsigned short ushort_t;
typedef unsigned int uint_t;

__device__ inline ushort_t f2bf(float f) {
    union { float f; uint_t u; } v; v.f = f;
    uint_t r = v.u + 0x7fff + ((v.u >> 16) & 1);   // round-to-nearest-even
    return (ushort_t)(r >> 16);
}
__device__ inline float bf2f(ushort_t h) {
    union { uint_t u; float f; } v; v.u = (uint_t)h << 16;
    return v.f;
}

// ============ Pass 1: per-block bucket histogram (LDS only) ============
__global__ __launch_bounds__(256) void k_cnt(const int* __restrict__ ei, int* __restrict__ bhist)
{
    __shared__ int lh[NBUCK];
    const int t = threadIdx.x;
    const int blk = blockIdx.x;
    for (int b = t; b < NBUCK; b += 256) lh[b] = 0;
    __syncthreads();
    const int base = blk * CHUNK;
    for (int i = t; i < CHUNK; i += 256) {
        const int dst = ei[N_EDGES + base + i];
        atomicAdd(&lh[dst / BUCK_W], 1);
    }
    __syncthreads();
    for (int b = t; b < NBUCK; b += 256) bhist[b * NBB + blk] = lh[b];
}

// ============ Pass 2a: scan each bucket's 256 block-counts ============
__global__ __launch_bounds__(256) void k_scanH(const int* __restrict__ bhist,
                                               int* __restrict__ boffB, int* __restrict__ btot)
{
    __shared__ int sh[256];
    const int t = threadIdx.x;
    const int b = blockIdx.x;
    const int v = bhist[b * NBB + t];
    sh[t] = v;
    __syncthreads();
    #pragma unroll
    for (int off = 1; off < 256; off <<= 1) {
        const int u = (t >= off) ? sh[t - off] : 0;
        __syncthreads();
        sh[t] += u;
        __syncthreads();
    }
    boffB[b * NBB + t] = sh[t] - v;
    if (t == 255) btot[b] = sh[255];
}

// ============ Pass 2b: scan bucket totals -> bucket start offsets ============
__global__ __launch_bounds__(1024) void k_scanH2(const int* __restrict__ btot,
                                                 int* __restrict__ bstart)
{
    __shared__ int sh[1024];
    const int t = threadIdx.x;
    const int v = (t < NBUCK) ? btot[t] : 0;
    sh[t] = v;
    __syncthreads();
    #pragma unroll
    for (int off = 1; off < 1024; off <<= 1) {
        const int u = (t >= off) ? sh[t - off] : 0;
        __syncthreads();
        sh[t] += u;
        __syncthreads();
    }
    if (t < NBUCK) bstart[t] = sh[t] - v;
    if (t == NBUCK - 1) bstart[NBUCK] = sh[t];
}

// ============ Pass 3: scatter edges into bucket-contiguous packed pairs ============
// pairsP[pos] = (dst % BUCK_W) << 17 | src
__global__ __launch_bounds__(256) void k_scat(const int* __restrict__ ei,
                                              const int* __restrict__ boffB,
                                              const int* __restrict__ bstart,
                                              int* __restrict__ pairsP)
{
    __shared__ int lcur[NBUCK];
    const int t = threadIdx.x;
    const int blk = blockIdx.x;
    for (int b = t; b < NBUCK; b += 256) lcur[b] = bstart[b] + boffB[b * NBB + blk];
    __syncthreads();
    const int base = blk * CHUNK;
    for (int i = t; i < CHUNK; i += 256) {
        const int src = ei[base + i];
        const int dst = ei[N_EDGES + base + i];
        const int b = dst / BUCK_W;
        const int pos = atomicAdd(&lcur[b], 1);
        pairsP[pos] = ((dst - b * BUCK_W) << 17) | src;
    }
}

// ============ Weight fusion: W' = W1b @ W1a  [32][256], b' = W1b@b1a + b1b ============
__global__ __launch_bounds__(256) void k_wfuse(
    const float* __restrict__ w1a_w, const float* __restrict__ w1a_b,
    const float* __restrict__ w1b_w, const float* __restrict__ w1b_b,
    float* __restrict__ wp, float* __restrict__ bp)
{
    __shared__ float wb_s[32][32];
    __shared__ float ba_s[32];
    const int t = threadIdx.x;
    for (int i = t; i < 1024; i += 256) wb_s[i >> 5][i & 31] = w1b_w[i];
    if (t < 32) ba_s[t] = w1a_b[t];
    __syncthreads();
    const int k = t;                       // 0..255
    for (int o = 0; o < 32; ++o) {
        float s = 0.f;
        #pragma unroll 8
        for (int c = 0; c < 32; ++c) s += wb_s[o][c] * w1a_w[c * 256 + k];
        wp[o * 256 + k] = s;
    }
    if (t < 32) {
        float s = 0.f;
        for (int c = 0; c < 32; ++c) s += wb_s[t][c] * ba_s[c];
        bp[t] = s + w1b_b[t];
    }
}

// ============ Layer 1 GEMM (single pass over x):
// h1b = bf16(x@W1a^T + b1a)  AND  out1 = x@W'^T + b'  in one block.
// Two transposed weight tiles (conflict-free); 67.6 KB LDS -> 2 blocks/CU.
__global__ __launch_bounds__(256) void k1_gemm(
    const float* __restrict__ x,
    const float* __restrict__ w1a_w, const float* __restrict__ w1a_b,
    const float* __restrict__ wp, const float* __restrict__ bp,
    ushort_t* __restrict__ h1b, float* __restrict__ out1)
{
    __shared__ float wsA[256][33];   // W1a^T
    __shared__ float wsB[256][33];   // W'^T

    const int t = threadIdx.x;
    const int node0 = (int)blockIdx.x * 256;

    for (int i = t; i < 32 * 256; i += 256) {
        const int o = i >> 8, k = i & 255;
        wsA[k][o] = w1a_w[i];
        wsB[k][o] = wp[i];
    }
    __syncthreads();

    const int og = t & 3;
    const int ng = t >> 2;
    const int o0 = og * 8;

    int nid[4]; bool val[4];
    #pragma unroll
    for (int j = 0; j < 4; ++j) { nid[j] = node0 + ng * 4 + j; val[j] = nid[j] < N_NODES; }

    float biasA[8], biasB[8];
    #pragma unroll
    for (int o = 0; o < 8; ++o) { biasA[o] = w1a_b[o0 + o]; biasB[o] = bp[o0 + o]; }

    float acc[4][8] = {};    // h accumulators
    float acc2[4][8] = {};   // out1 accumulators
    for (int kc = 0; kc < 64; ++kc) {
        float4 x4[4];
        #pragma unroll
        for (int j = 0; j < 4; ++j) {
            x4[j] = val[j] ? ((const float4*)(x + (size_t)nid[j] * IN_F))[kc]
                           : make_float4(0.f, 0.f, 0.f, 0.f);
        }
        #pragma unroll
        for (int u = 0; u < 4; ++u) {
            const int k = kc * 4 + u;
            const float4 aA = *(const float4*)&wsA[k][o0];
            const float4 aB = *(const float4*)&wsA[k][o0 + 4];
            const float4 bA = *(const float4*)&wsB[k][o0];
            const float4 bB = *(const float4*)&wsB[k][o0 + 4];
            #pragma unroll
            for (int j = 0; j < 4; ++j) {
                const float xv = (u == 0) ? x4[j].x : (u == 1) ? x4[j].y
                               : (u == 2) ? x4[j].z : x4[j].w;
                acc[j][0]  += xv * aA.x; acc[j][1]  += xv * aA.y;
                acc[j][2]  += xv * aA.z; acc[j][3]  += xv * aA.w;
                acc[j][4]  += xv * aB.x; acc[j][5]  += xv * aB.y;
                acc[j][6]  += xv * aB.z; acc[j][7]  += xv * aB.w;
                acc2[j][0] += xv * bA.x; acc2[j][1] += xv * bA.y;
                acc2[j][2] += xv * bA.z; acc2[j][3] += xv * bA.w;
                acc2[j][4] += xv * bB.x; acc2[j][5] += xv * bB.y;
                acc2[j][6] += xv * bB.z; acc2[j][7] += xv * bB.w;
            }
        }
    }

    #pragma unroll
    for (int j = 0; j < 4; ++j) {
        if (!val[j]) continue;
        uint4 pk;
        pk.x = (uint_t)f2bf(acc[j][0] + biasA[0]) | ((uint_t)f2bf(acc[j][1] + biasA[1]) << 16);
        pk.y = (uint_t)f2bf(acc[j][2] + biasA[2]) | ((uint_t)f2bf(acc[j][3] + biasA[3]) << 16);
        pk.z = (uint_t)f2bf(acc[j][4] + biasA[4]) | ((uint_t)f2bf(acc[j][5] + biasA[5]) << 16);
        pk.w = (uint_t)f2bf(acc[j][6] + biasA[6]) | ((uint_t)f2bf(acc[j][7] + biasA[7]) << 16);
        *(uint4*)(h1b + (size_t)nid[j] * HID + o0) = pk;
        float* dst = out1 + (size_t)nid[j] * HID + o0;
        *(float4*)dst       = make_float4(acc2[j][0] + biasB[0], acc2[j][1] + biasB[1],
                                          acc2[j][2] + biasB[2], acc2[j][3] + biasB[3]);
        *(float4*)(dst + 4) = make_float4(acc2[j][4] + biasB[4], acc2[j][5] + biasB[5],
                                          acc2[j][6] + biasB[6], acc2[j][7] + biasB[7]);
    }
}

// ============ Aggregate layer 1: in-LDS counting sort, register accumulate ============
__global__ __launch_bounds__(256) void k_agg32(const int* __restrict__ bstart,
                                               const int* __restrict__ pairsP,
                                               const ushort_t* __restrict__ h1b,
                                               float* __restrict__ out1)
{
    __shared__ int cnt[128];
    __shared__ int off[129];
    __shared__ int srt[MAXE];
    const int t = threadIdx.x;
    const int b = blockIdx.x;
    const int c = t & 31;
    const int grp = t >> 5;                 // 8 groups of 32 lanes

    const int e0g = bstart[b];
    const int e1g = bstart[b + 1];

    for (int ch0 = e0g; ch0 < e1g; ch0 += MAXE) {
        const int ce = (ch0 + MAXE < e1g) ? (ch0 + MAXE) : e1g;
        const int cn = ce - ch0;

        if (t < 128) cnt[t] = 0;
        __syncthreads();
        for (int i = t; i < cn; i += 256)
            atomicAdd(&cnt[pairsP[ch0 + i] >> 17], 1);
        __syncthreads();
        {
            int v = (t < 128) ? cnt[t] : 0;
            if (t < 128) off[t] = v;
            __syncthreads();
            #pragma unroll
            for (int o = 1; o < 128; o <<= 1) {
                int u = 0;
                if (t < 128 && t >= o) u = off[t - o];
                __syncthreads();
                if (t < 128) off[t] += u;
                __syncthreads();
            }
            if (t < 128) {
                const int inc = off[t];
                off[t] = inc - v;
                cnt[t] = inc - v;
                if (t == 127) off[128] = inc;
            }
        }
        __syncthreads();
        for (int i = t; i < cn; i += 256) {
            const int p = pairsP[ch0 + i];
            const int pos = atomicAdd(&cnt[p >> 17], 1);
            srt[pos] = p & 0x1FFFF;
        }
        __syncthreads();
        for (int n = grp; n < BUCK_W; n += 8) {
            const int e0 = off[n];
            const int e1 = off[n + 1];
            float acc = 0.f, acc2 = 0.f;
            int e = e0;
            for (; e + 1 < e1; e += 2) {
                const int s0 = srt[e];
                const int s1 = srt[e + 1];
                const float v0 = bf2f(h1b[(size_t)s0 * HID + c]);
                const float v1 = bf2f(h1b[(size_t)s1 * HID + c]);
                acc += v0; acc2 += v1;
            }
            if (e < e1) acc += bf2f(h1b[(size_t)srt[e] * HID + c]);
            acc += acc2;
            out1[((size_t)b * BUCK_W + n) * HID + c] += acc;
        }
        __syncthreads();
    }
}

// ============ Layer 2 dense ============
__global__ __launch_bounds__(256) void k3_layer2_dense(
    const float* __restrict__ out1,
    const float* __restrict__ w2a_w, const float* __restrict__ w2a_b,
    const float* __restrict__ w2b_w, const float* __restrict__ w2b_b,
    ushort_t* __restrict__ h2b, float* __restrict__ out2)
{
    __shared__ float rs[64][33];
    __shared__ float h2s[64][17];
    __shared__ float wa[16][33];
    __shared__ float wb[16][17];

    const int t = threadIdx.x;
    const int node0 = blockIdx.x * 64;
    const int nrem = N_NODES - node0;

    for (int i = t; i < 16 * 32; i += 256)
        wa[i >> 5][i & 31] = w2a_w[i];
    if (t < 16 * 16) wb[t >> 4][t & 15] = w2b_w[t];
    for (int i = t; i < 64 * 32; i += 256) {
        int r = i >> 5, c = i & 31;
        float v = 0.f;
        if (r < nrem) v = out1[(size_t)(node0 + r) * HID + c];
        rs[r][c] = fmaxf(v, 0.f);
    }
    __syncthreads();

    const int o = t & 15;
    const int g = t >> 4;

    const float ba = w2a_b[o];
    float acc[4] = {};
    for (int c = 0; c < 32; ++c) {
        const float w = wa[o][c];
        #pragma unroll
        for (int j = 0; j < 4; ++j) acc[j] += rs[g * 4 + j][c] * w;
    }
    #pragma unroll
    for (int j = 0; j < 4; ++j) {
        const int ln = g * 4 + j;
        const float v = acc[j] + ba;
        h2s[ln][o] = v;
        if (ln < nrem) h2b[(size_t)(node0 + ln) * OUTC + o] = f2bf(v);
    }
    __syncthreads();

    const float bbv = w2b_b[o];
    float f[4] = {};
    for (int c = 0; c < 16; ++c) {
        const float w = wb[o][c];
        #pragma unroll
        for (int j = 0; j < 4; ++j) f[j] += h2s[g * 4 + j][c] * w;
    }
    #pragma unroll
    for (int j = 0; j < 4; ++j) {
        const int ln = g * 4 + j;
        if (ln < nrem) out2[(size_t)(node0 + ln) * OUTC + o] = f[j] + bbv;
    }
}

// ============ Aggregate layer 2 (sorted, register acc) + fused log_softmax ============
__global__ __launch_bounds__(256) void k_agg16_sm(const int* __restrict__ bstart,
                                                  const int* __restrict__ pairsP,
                                                  const ushort_t* __restrict__ h2b,
                                                  float* __restrict__ out2)
{
    __shared__ int cnt[128];
    __shared__ int off[129];
    __shared__ int srt[MAXE];
    const int t = threadIdx.x;
    const int b = blockIdx.x;
    const int c = t & 15;
    const int grp = t >> 4;                 // 16 groups of 16 lanes

    const int e0g = bstart[b];
    const int e1g = bstart[b + 1];

    for (int ch0 = e0g; ch0 < e1g; ch0 += MAXE) {
        const int ce = (ch0 + MAXE < e1g) ? (ch0 + MAXE) : e1g;
        const int cn = ce - ch0;
        const bool last = (ce == e1g);

        if (t < 128) cnt[t] = 0;
        __syncthreads();
        for (int i = t; i < cn; i += 256)
            atomicAdd(&cnt[pairsP[ch0 + i] >> 17], 1);
        __syncthreads();
        {
            int v = (t < 128) ? cnt[t] : 0;
            if (t < 128) off[t] = v;
            __syncthreads();
            #pragma unroll
            for (int o = 1; o < 128; o <<= 1) {
                int u = 0;
                if (t < 128 && t >= o) u = off[t - o];
                __syncthreads();
                if (t < 128) off[t] += u;
                __syncthreads();
            }
            if (t < 128) {
                const int inc = off[t];
                off[t] = inc - v;
                cnt[t] = inc - v;
                if (t == 127) off[128] = inc;
            }
        }
        __syncthreads();
        for (int i = t; i < cn; i += 256) {
            const int p = pairsP[ch0 + i];
            const int pos = atomicAdd(&cnt[p >> 17], 1);
            srt[pos] = p & 0x1FFFF;
        }
        __syncthreads();

        for (int n = grp; n < BUCK_W; n += 16) {
            const int e0 = off[n];
            const int e1 = off[n + 1];
            float acc = 0.f, acc2 = 0.f;
            int e = e0;
            for (; e + 1 < e1; e += 2) {
                const int s0 = srt[e];
                const int s1 = srt[e + 1];
                const float v0 = bf2f(h2b[(size_t)s0 * OUTC + c]);
                const float v1 = bf2f(h2b[(size_t)s1 * OUTC + c]);
                acc += v0; acc2 += v1;
            }
            if (e < e1) acc += bf2f(h2b[(size_t)srt[e] * OUTC + c]);
            acc += acc2;

            const size_t oidx = ((size_t)b * BUCK_W + n) * OUTC + c;
            if (!last) {
                out2[oidx] += acc;
            } else {
                const float val = out2[oidx] + acc;
                float m = val;
                #pragma unroll
                for (int o = 8; o > 0; o >>= 1)
                    m = fmaxf(m, __shfl_xor(m, o, 16));
                float s = expf(val - m);
                #pragma unroll
                for (int o = 8; o > 0; o >>= 1)
                    s += __shfl_xor(s, o, 16);
                const float lse = m + logf(s);
                out2[oidx] = val - lse;
            }
        }
        __syncthreads();
    }
}

extern "C" void kernel_launch(void* const* d_in, const int* in_sizes, int n_in,
                              void* d_out, int out_size, void* d_ws, size_t ws_size,
                              hipStream_t stream)
{
    const float* x      = (const float*)d_in[0];
    const float* w1a_w  = (const float*)d_in[1];
    const float* w1a_b  = (const float*)d_in[2];
    const float* w1b_w  = (const float*)d_in[3];
    const float* w1b_b  = (const float*)d_in[4];
    const float* w2a_w  = (const float*)d_in[5];
    const float* w2a_b  = (const float*)d_in[6];
    const float* w2b_w  = (const float*)d_in[7];
    const float* w2b_b  = (const float*)d_in[8];
    const int*   ei     = (const int*)d_in[9];
    float* out = (float*)d_out;

    // workspace (~31 MB)
    float*    out1   = (float*)d_ws;                              // 12.8 MB
    ushort_t* h1b    = (ushort_t*)(out1 + (size_t)N_NODES * HID); // 6.4 MB
    ushort_t* h2b    = h1b + (size_t)N_NODES * HID;               // 3.2 MB
    int*      pairsP = (int*)(h2b + (size_t)N_NODES * OUTC);      // 6.4 MB
    int*      bhist  = pairsP + N_EDGES;                          // 1 MB
    int*      boffB  = bhist + NBUCK * NBB;                       // 1 MB
    int*      btot   = boffB + NBUCK * NBB;                       // 1000
    int*      bstart = btot + NBUCK;                              // 1001
    float*    wp     = (float*)(bstart + NBUCK + 1);              // 32*256 f32
    float*    bp     = wp + 32 * 256;                             // 32 f32

    k_cnt   <<<NBB, 256, 0, stream>>>(ei, bhist);
    k_scanH <<<NBUCK, 256, 0, stream>>>(bhist, boffB, btot);
    k_scanH2<<<1, 1024, 0, stream>>>(btot, bstart);
    k_scat  <<<NBB, 256, 0, stream>>>(ei, boffB, bstart, pairsP);
    k_wfuse <<<1, 256, 0, stream>>>(w1a_w, w1a_b, w1b_w, w1b_b, wp, bp);

    k1_gemm<<<(N_NODES + 255) / 256, 256, 0, stream>>>(x, w1a_w, w1a_b, wp, bp, h1b, out1);
    k_agg32<<<NBUCK, 256, 0, stream>>>(bstart, pairsP, h1b, out1);
    k3_layer2_dense<<<(N_NODES + 63) / 64, 256, 0, stream>>>(out1, w2a_w, w2a_b, w2b_w, w2b_b, h2b, out);
    k_agg16_sm<<<NBUCK, 256, 0, stream>>>(bstart, pairsP, h2b, out);
}